// Round 5
// baseline (54002.039 us; speedup 1.0000x reference)
//
#include <hip/hip_runtime.h>

#define H    512
#define DOBS 256
#define BATCH 32
#define SEQ  2048

typedef float f8 __attribute__((ext_vector_type(8)));

// ---------------- C[M][N] = A[M][K] @ B[N][K]^T + bias[N] ----------------
// 128x128 tile, 8x8 accumulators (round-3 verified).
__global__ __launch_bounds__(256) void gemm_bias_k(const float* __restrict__ A,
                                                   const float* __restrict__ B,
                                                   const float* __restrict__ bias,
                                                   float* __restrict__ C,
                                                   int M, int N, int K) {
  __shared__ float As[16][132];
  __shared__ float Bs[16][132];
  const int m0 = blockIdx.x * 128;
  const int n0 = blockIdx.y * 128;
  const int t  = threadIdx.x;
  const int tm = (t >> 4) * 4;
  const int tn = (t & 15) * 4;
  const int lrow = t >> 2;
  const int lcol = (t & 3) * 4;

  float acc[8][8] = {};

  for (int k0 = 0; k0 < K; k0 += 16) {
    float4 a0 = *(const float4*)&A[(size_t)(m0 + lrow)      * K + k0 + lcol];
    float4 a1 = *(const float4*)&A[(size_t)(m0 + lrow + 64) * K + k0 + lcol];
    float4 b0 = *(const float4*)&B[(size_t)(n0 + lrow)      * K + k0 + lcol];
    float4 b1 = *(const float4*)&B[(size_t)(n0 + lrow + 64) * K + k0 + lcol];
    __syncthreads();
    As[lcol + 0][lrow] = a0.x; As[lcol + 1][lrow] = a0.y;
    As[lcol + 2][lrow] = a0.z; As[lcol + 3][lrow] = a0.w;
    As[lcol + 0][lrow + 64] = a1.x; As[lcol + 1][lrow + 64] = a1.y;
    As[lcol + 2][lrow + 64] = a1.z; As[lcol + 3][lrow + 64] = a1.w;
    Bs[lcol + 0][lrow] = b0.x; Bs[lcol + 1][lrow] = b0.y;
    Bs[lcol + 2][lrow] = b0.z; Bs[lcol + 3][lrow] = b0.w;
    Bs[lcol + 0][lrow + 64] = b1.x; Bs[lcol + 1][lrow + 64] = b1.y;
    Bs[lcol + 2][lrow + 64] = b1.z; Bs[lcol + 3][lrow + 64] = b1.w;
    __syncthreads();
#pragma unroll
    for (int k = 0; k < 16; ++k) {
      float4 aA = *(const float4*)&As[k][tm];
      float4 aB = *(const float4*)&As[k][tm + 64];
      float4 bA = *(const float4*)&Bs[k][tn];
      float4 bB = *(const float4*)&Bs[k][tn + 64];
      float av[8] = {aA.x, aA.y, aA.z, aA.w, aB.x, aB.y, aB.z, aB.w};
      float bv[8] = {bA.x, bA.y, bA.z, bA.w, bB.x, bB.y, bB.z, bB.w};
#pragma unroll
      for (int i = 0; i < 8; ++i)
#pragma unroll
        for (int j = 0; j < 8; ++j)
          acc[i][j] = fmaf(av[i], bv[j], acc[i][j]);
    }
  }

  float4 bbA = *(const float4*)&bias[n0 + tn];
  float4 bbB = *(const float4*)&bias[n0 + tn + 64];
#pragma unroll
  for (int i = 0; i < 8; ++i) {
    int row = m0 + ((i < 4) ? (tm + i) : (64 + tm + i - 4));
    float4 c0, c1;
    c0.x = acc[i][0] + bbA.x; c0.y = acc[i][1] + bbA.y;
    c0.z = acc[i][2] + bbA.z; c0.w = acc[i][3] + bbA.w;
    c1.x = acc[i][4] + bbB.x; c1.y = acc[i][5] + bbB.y;
    c1.z = acc[i][6] + bbB.z; c1.w = acc[i][7] + bbB.w;
    *(float4*)&C[(size_t)row * N + n0 + tn]      = c0;
    *(float4*)&C[(size_t)row * N + n0 + tn + 64] = c1;
  }
}

// ---------------- recurrence: ONE 1024-thread WG per chain ----------------
// The whole per-step all-to-all (h_{t-1} -> h_t) lives inside one CU:
//   * lane owns output n = wave*32 + (l>>1), k-half c2 = l&1 (256 weights =
//     32 f8 = 256 VGPR/lane, row-major from Whh -> no transpose).
//     16 waves = 4/SIMD -> per-wave VGPR budget 2048/4 = 512: no spill
//     (round-4 lesson: verify live-set vs allocation).
//   * NO cross-WG protocol: no exchange flags, no agent atomics, no polling.
//     h broadcast via LDS double-buffer (write buf[t&1], read buf[(t-1)&1],
//     ONE raw barrier per step, lgkmcnt-only -> xp/h global ops stay in
//     flight across it).
//   * per-step critical path = VALU issue: 4 waves/SIMD x 256 FMA x 2cy
//     ~ 2048 cy -> ~0.85 us/step.
//   * LDS reads: 2 addresses per ds_read_b128 (32-lane broadcast each),
//     2-way bank alias = free. h-store: 32 contiguous dwords per wave.
//   * xp read at step top (row t of hid = gemm1 output), consumed at step
//     end (~2000cy in flight covers cold HBM); then overwritten with h_t.
__global__ __launch_bounds__(1024, 1) void rnn_rec_k(float* __restrict__ hid,
                                                     const float* __restrict__ Whh,
                                                     const float* __restrict__ bh) {
  const int b   = blockIdx.x;
  const int tid = threadIdx.x;
  const int l   = tid & 63;
  const int n   = (tid >> 6) * 32 + (l >> 1);  // output column 0..511
  const int c2  = l & 1;                       // k-half: [256*c2, 256*c2+256)
  const bool lead = (c2 == 0);

  __shared__ __align__(16) float bufs[2][H];

  float* hb = hid + (size_t)b * SEQ * H;

  // weight preload, row-major: Wv[i][j] = Whh[n][c2*256 + 8i + j]
  f8 Wv[32];
  {
    const float* wp = Whh + (size_t)n * H + c2 * 256;
#pragma unroll
    for (int i = 0; i < 32; ++i) Wv[i] = *(const f8*)(wp + 8 * i);
  }
  const float bn = bh[n];

  for (int t = 0; t < SEQ; ++t) {
    // xp for this step (gemm1 output); issued early, used ~2000cy later
    float xp = lead ? hb[(size_t)t * H + n] : 0.f;

    float r = 0.f;
    if (t > 0) {
      const float4* hp = (const float4*)(bufs[(t - 1) & 1] + (c2 << 8));
      float a0 = 0.f, a1 = 0.f, a2 = 0.f, a3 = 0.f;
#pragma unroll
      for (int i = 0; i < 32; ++i) {
        float4 hA = hp[2 * i];
        float4 hB = hp[2 * i + 1];
        a0 = fmaf(Wv[i][0], hA.x, a0);
        a1 = fmaf(Wv[i][1], hA.y, a1);
        a2 = fmaf(Wv[i][2], hA.z, a2);
        a3 = fmaf(Wv[i][3], hA.w, a3);
        a0 = fmaf(Wv[i][4], hB.x, a0);
        a1 = fmaf(Wv[i][5], hB.y, a1);
        a2 = fmaf(Wv[i][6], hB.z, a2);
        a3 = fmaf(Wv[i][7], hB.w, a3);
      }
      r = (a0 + a1) + (a2 + a3);
      r += __shfl_xor(r, 1, 64);  // combine the two k-halves
    }

    if (lead) {
      float hv = fmaxf(r + xp + bn, 0.f);
      bufs[t & 1][n] = hv;             // broadcast for step t+1
      hb[(size_t)t * H + n] = hv;      // hidden_arr (fire-and-forget)
    }

    // LDS-only barrier: h writes visible; global ops stay in flight.
    asm volatile("s_waitcnt lgkmcnt(0)" ::: "memory");
    __builtin_amdgcn_s_barrier();
    asm volatile("" ::: "memory");
  }
}

// ---------------- grid-strided in-place row softmax over 512 cols ---------
__global__ __launch_bounds__(256) void softmax_k(float* __restrict__ Z, int nrows) {
  __shared__ float smax[4];
  __shared__ float ssum[4];
  const int t = threadIdx.x;
  const int wave = t >> 6, lane = t & 63;
  const float LOG2E = 1.44269504088896f;
  for (int r = blockIdx.x; r < nrows; r += gridDim.x) {
    float* row = Z + (size_t)r * H;
    float2 v = *(float2*)&row[2 * t];
    float m = fmaxf(v.x, v.y);
#pragma unroll
    for (int o = 32; o > 0; o >>= 1) m = fmaxf(m, __shfl_xor(m, o, 64));
    if (lane == 0) smax[wave] = m;
    __syncthreads();
    m = fmaxf(fmaxf(smax[0], smax[1]), fmaxf(smax[2], smax[3]));
    float ex = exp2f((v.x - m) * LOG2E);
    float ey = exp2f((v.y - m) * LOG2E);
    float s = ex + ey;
#pragma unroll
    for (int o = 32; o > 0; o >>= 1) s += __shfl_xor(s, o, 64);
    if (lane == 0) ssum[wave] = s;
    __syncthreads();
    float inv = 1.0f / (ssum[0] + ssum[1] + ssum[2] + ssum[3]);
    float2 out;
    out.x = ex * inv;
    out.y = ey * inv;
    *(float2*)&row[2 * t] = out;
    __syncthreads();  // protect smax/ssum reuse next row
  }
}

extern "C" void kernel_launch(void* const* d_in, const int* in_sizes, int n_in,
                              void* d_out, int out_size, void* d_ws, size_t ws_size,
                              hipStream_t stream) {
  const float* x     = (const float*)d_in[0];
  const float* Whx_w = (const float*)d_in[1];
  const float* Whx_b = (const float*)d_in[2];
  const float* Whh_w = (const float*)d_in[3];
  const float* Whh_b = (const float*)d_in[4];
  const float* Woh_w = (const float*)d_in[5];
  const float* Woh_b = (const float*)d_in[6];

  float* y   = (float*)d_out;                           // output_arr
  float* hid = (float*)d_out + (size_t)BATCH * SEQ * H; // hidden_arr: xp then h

  const int M = BATCH * SEQ;  // 65536

  gemm_bias_k<<<dim3(M / 128, H / 128), 256, 0, stream>>>(x, Whx_w, Whx_b, hid, M, H, DOBS);
  rnn_rec_k<<<BATCH, 1024, 0, stream>>>(hid, Whh_w, Whh_b);
  gemm_bias_k<<<dim3(M / 128, H / 128), 256, 0, stream>>>(hid, Woh_w, Woh_b, y, M, H, H);
  softmax_k<<<2048, 256, 0, stream>>>(y, M);
}

// Round 7
// 3855.953 us; speedup vs baseline: 14.0048x; 14.0048x over previous
//
#include <hip/hip_runtime.h>

#define H    512
#define DOBS 256
#define BATCH 32
#define SEQ  2048
#define NSLICE 8   // WGs per chain
#define NS 64      // outputs per WG

typedef float f8 __attribute__((ext_vector_type(8)));

#define PLD(p)    __hip_atomic_load((p), __ATOMIC_RELAXED, __HIP_MEMORY_SCOPE_AGENT)
#define PST(p, v) __hip_atomic_store((p), (v), __ATOMIC_RELAXED, __HIP_MEMORY_SCOPE_AGENT)

// ---------------- transpose 512x512: Wt[k][n] = W[n][k] ----------------
__global__ __launch_bounds__(256) void transpose_k(const float* __restrict__ W,
                                                   float* __restrict__ Wt) {
  __shared__ float tile[32][33];
  int tx  = threadIdx.x & 31;
  int ty4 = (threadIdx.x >> 5) * 4;
  int bx = blockIdx.x * 32;
  int by = blockIdx.y * 32;
#pragma unroll
  for (int i = 0; i < 4; ++i)
    tile[ty4 + i][tx] = W[(by + ty4 + i) * H + bx + tx];
  __syncthreads();
#pragma unroll
  for (int i = 0; i < 4; ++i)
    Wt[(bx + ty4 + i) * H + by + tx] = tile[tx][ty4 + i];
}

// ---------------- C[M][N] = A[M][K] @ B[N][K]^T + bias[N] ----------------
// 128x128 tile, 8x8 accumulators (round-3 verified).
__global__ __launch_bounds__(256) void gemm_bias_k(const float* __restrict__ A,
                                                   const float* __restrict__ B,
                                                   const float* __restrict__ bias,
                                                   float* __restrict__ C,
                                                   int M, int N, int K) {
  __shared__ float As[16][132];
  __shared__ float Bs[16][132];
  const int m0 = blockIdx.x * 128;
  const int n0 = blockIdx.y * 128;
  const int t  = threadIdx.x;
  const int tm = (t >> 4) * 4;
  const int tn = (t & 15) * 4;
  const int lrow = t >> 2;
  const int lcol = (t & 3) * 4;

  float acc[8][8] = {};

  for (int k0 = 0; k0 < K; k0 += 16) {
    float4 a0 = *(const float4*)&A[(size_t)(m0 + lrow)      * K + k0 + lcol];
    float4 a1 = *(const float4*)&A[(size_t)(m0 + lrow + 64) * K + k0 + lcol];
    float4 b0 = *(const float4*)&B[(size_t)(n0 + lrow)      * K + k0 + lcol];
    float4 b1 = *(const float4*)&B[(size_t)(n0 + lrow + 64) * K + k0 + lcol];
    __syncthreads();
    As[lcol + 0][lrow] = a0.x; As[lcol + 1][lrow] = a0.y;
    As[lcol + 2][lrow] = a0.z; As[lcol + 3][lrow] = a0.w;
    As[lcol + 0][lrow + 64] = a1.x; As[lcol + 1][lrow + 64] = a1.y;
    As[lcol + 2][lrow + 64] = a1.z; As[lcol + 3][lrow + 64] = a1.w;
    Bs[lcol + 0][lrow] = b0.x; Bs[lcol + 1][lrow] = b0.y;
    Bs[lcol + 2][lrow] = b0.z; Bs[lcol + 3][lrow] = b0.w;
    Bs[lcol + 0][lrow + 64] = b1.x; Bs[lcol + 1][lrow + 64] = b1.y;
    Bs[lcol + 2][lrow + 64] = b1.z; Bs[lcol + 3][lrow + 64] = b1.w;
    __syncthreads();
#pragma unroll
    for (int k = 0; k < 16; ++k) {
      float4 aA = *(const float4*)&As[k][tm];
      float4 aB = *(const float4*)&As[k][tm + 64];
      float4 bA = *(const float4*)&Bs[k][tn];
      float4 bB = *(const float4*)&Bs[k][tn + 64];
      float av[8] = {aA.x, aA.y, aA.z, aA.w, aB.x, aB.y, aB.z, aB.w};
      float bv[8] = {bA.x, bA.y, bA.z, bA.w, bB.x, bB.y, bB.z, bB.w};
#pragma unroll
      for (int i = 0; i < 8; ++i)
#pragma unroll
        for (int j = 0; j < 8; ++j)
          acc[i][j] = fmaf(av[i], bv[j], acc[i][j]);
    }
  }

  float4 bbA = *(const float4*)&bias[n0 + tn];
  float4 bbB = *(const float4*)&bias[n0 + tn + 64];
#pragma unroll
  for (int i = 0; i < 8; ++i) {
    int row = m0 + ((i < 4) ? (tm + i) : (64 + tm + i - 4));
    float4 c0, c1;
    c0.x = acc[i][0] + bbA.x; c0.y = acc[i][1] + bbA.y;
    c0.z = acc[i][2] + bbA.z; c0.w = acc[i][3] + bbA.w;
    c1.x = acc[i][4] + bbB.x; c1.y = acc[i][5] + bbB.y;
    c1.z = acc[i][6] + bbB.z; c1.w = acc[i][7] + bbB.w;
    *(float4*)&C[(size_t)row * N + n0 + tn]      = c0;
    *(float4*)&C[(size_t)row * N + n0 + tn + 64] = c1;
  }
}

// ---------------- recurrence: 32 chains x 8 slices ------------------------
// Round-2 verified structure (2700us): chunked agent-scope polls, stale-line
// prefetch, one barrier, wave0 finalize, VGPR-resident weights. ONE change:
// 4-deep STAGGERED poll. The old loop re-sampled only once per MALL round
// trip L (~600cy) because each iteration drained vmcnt(0). Now 4 load-pairs
// stay in flight; we check the oldest while 3 newer pairs are outstanding
// (compiler's counted s_waitcnt waits only for the checked pair), so the
// sampling interval is ~L/4. This cuts both the mean observation delay and
// the max-of-8-WGs jitter tail that sets the chain period. Named scalars
// (not arrays) so everything stays in VGPRs (rule: runtime-indexed arrays
// spill to scratch). Worst case (compiler emits vmcnt(0)) == round-2.
__global__ __launch_bounds__(256, 1) void rnn_rec_k(float* __restrict__ hid,
                                                    float* __restrict__ exch,
                                                    const float* __restrict__ Wt,
                                                    const float* __restrict__ bias) {
  const int b     = blockIdx.x & (BATCH - 1);
  const int slice = blockIdx.x >> 5;
  const int n0    = slice * NS;
  const int tid   = threadIdx.x;
  const int w     = tid >> 6;   // wave 0..3 -> k chunk of 128
  const int l     = tid & 63;

  __shared__ __align__(16) float shh[H];
  __shared__ float sh_part[2][4][NS];

  float* hb = hid  + (size_t)b * SEQ * H;
  float* eb = exch + (size_t)b * SEQ * H;

  // one-time weight preload into SSA vectors: Wv[i][j] = Wt[w*128+8i+j][n0+l]
  f8 Wv[16];
  {
    const float* wp = Wt + (size_t)(w * 128) * H + n0 + l;
#pragma unroll
    for (int i = 0; i < 16; ++i) {
#pragma unroll
      for (int j = 0; j < 8; ++j)
        Wv[i][j] = wp[(size_t)(i * 8 + j) * H];
    }
  }
  const float bn = bias[n0 + l];

  const float4* sh4 = (const float4*)&shh[w * 128];

  for (int t = 0; t < SEQ; ++t) {
    float xp = 0.f;
    if (w == 0) xp = hb[(size_t)t * H + n0 + l];  // prefetch xp_t

    // L3 prefetch of this step's exchange chunk (polled at t+1) — verified
    // +700us in round 2. Fills MALL under this step's poll+FMA.
    const float* pf = eb + (size_t)t * H + w * 128;
    float p0 = pf[l];
    float p1 = pf[64 + l];

    float partial = 0.f;
    if (t > 0) {
      // 4-deep staggered poll of this wave's 128-wide chunk of (h_{t-1}+1)
      const float* ep = eb + (size_t)(t - 1) * H + w * 128;
      float v0, v1;
      {
        float a0 = PLD(ep + l), a1 = PLD(ep + 64 + l);
        float b0 = PLD(ep + l), b1 = PLD(ep + 64 + l);
        float c0 = PLD(ep + l), c1 = PLD(ep + 64 + l);
        float d0 = PLD(ep + l), d1 = PLD(ep + 64 + l);
        for (;;) {
          if (!__any(!(a0 >= 1.0f && a1 >= 1.0f))) { v0 = a0; v1 = a1; break; }
          a0 = PLD(ep + l); a1 = PLD(ep + 64 + l);
          if (!__any(!(b0 >= 1.0f && b1 >= 1.0f))) { v0 = b0; v1 = b1; break; }
          b0 = PLD(ep + l); b1 = PLD(ep + 64 + l);
          if (!__any(!(c0 >= 1.0f && c1 >= 1.0f))) { v0 = c0; v1 = c1; break; }
          c0 = PLD(ep + l); c1 = PLD(ep + 64 + l);
          if (!__any(!(d0 >= 1.0f && d1 >= 1.0f))) { v0 = d0; v1 = d1; break; }
          d0 = PLD(ep + l); d1 = PLD(ep + 64 + l);
        }
      }
      // wave-local LDS broadcast (same wave produces & consumes its region)
      shh[w * 128 + l]      = v0 - 1.0f;
      shh[w * 128 + 64 + l] = v1 - 1.0f;
      asm volatile("s_waitcnt lgkmcnt(0)" ::: "memory");

      float a0 = 0.f, a1 = 0.f, a2 = 0.f, a3 = 0.f;
#pragma unroll
      for (int i = 0; i < 16; ++i) {
        float4 hA = sh4[2 * i];
        float4 hB = sh4[2 * i + 1];
        a0 = fmaf(Wv[i][0], hA.x, a0);
        a1 = fmaf(Wv[i][1], hA.y, a1);
        a2 = fmaf(Wv[i][2], hA.z, a2);
        a3 = fmaf(Wv[i][3], hA.w, a3);
        a0 = fmaf(Wv[i][4], hB.x, a0);
        a1 = fmaf(Wv[i][5], hB.y, a1);
        a2 = fmaf(Wv[i][6], hB.z, a2);
        a3 = fmaf(Wv[i][7], hB.w, a3);
      }
      partial = (a0 + a1) + (a2 + a3);
    }

    sh_part[t & 1][w][l] = partial;
    // keep prefetch alive; barrier's vmcnt(0) drain overlaps its fill with
    // the poll+FMA phase above.
    asm volatile("" :: "v"(p0), "v"(p1));
    __syncthreads();  // one barrier per step; parity protects reuse

    if (w == 0) {
      float v = sh_part[t & 1][0][l] + sh_part[t & 1][1][l]
              + sh_part[t & 1][2][l] + sh_part[t & 1][3][l] + xp + bn;
      float hv = fmaxf(v, 0.f);
      // publish h+1 (self-flagging) for peers
      PST(&eb[(size_t)t * H + n0 + l], hv + 1.0f);
      // clean h for the output / next GEMM
      hb[(size_t)t * H + n0 + l] = hv;
    }
  }
}

// ---------------- grid-strided in-place row softmax over 512 cols ---------
__global__ __launch_bounds__(256) void softmax_k(float* __restrict__ Z, int nrows) {
  __shared__ float smax[4];
  __shared__ float ssum[4];
  const int t = threadIdx.x;
  const int wave = t >> 6, lane = t & 63;
  const float LOG2E = 1.44269504088896f;
  for (int r = blockIdx.x; r < nrows; r += gridDim.x) {
    float* row = Z + (size_t)r * H;
    float2 v = *(float2*)&row[2 * t];
    float m = fmaxf(v.x, v.y);
#pragma unroll
    for (int o = 32; o > 0; o >>= 1) m = fmaxf(m, __shfl_xor(m, o, 64));
    if (lane == 0) smax[wave] = m;
    __syncthreads();
    m = fmaxf(fmaxf(smax[0], smax[1]), fmaxf(smax[2], smax[3]));
    float ex = exp2f((v.x - m) * LOG2E);
    float ey = exp2f((v.y - m) * LOG2E);
    float s = ex + ey;
#pragma unroll
    for (int o = 32; o > 0; o >>= 1) s += __shfl_xor(s, o, 64);
    if (lane == 0) ssum[wave] = s;
    __syncthreads();
    float inv = 1.0f / (ssum[0] + ssum[1] + ssum[2] + ssum[3]);
    float2 out;
    out.x = ex * inv;
    out.y = ey * inv;
    *(float2*)&row[2 * t] = out;
    __syncthreads();  // protect smax/ssum reuse next row
  }
}

extern "C" void kernel_launch(void* const* d_in, const int* in_sizes, int n_in,
                              void* d_out, int out_size, void* d_ws, size_t ws_size,
                              hipStream_t stream) {
  const float* x     = (const float*)d_in[0];
  const float* Whx_w = (const float*)d_in[1];
  const float* Whx_b = (const float*)d_in[2];
  const float* Whh_w = (const float*)d_in[3];
  const float* Whh_b = (const float*)d_in[4];
  const float* Woh_w = (const float*)d_in[5];
  const float* Woh_b = (const float*)d_in[6];

  float* y   = (float*)d_out;                           // output_arr; doubles as h+1 exchange
  float* hid = (float*)d_out + (size_t)BATCH * SEQ * H; // hidden_arr: xp then h
  float* Wt  = (float*)d_ws;                            // 1 MB

  const int M = BATCH * SEQ;  // 65536

  transpose_k<<<dim3(16, 16), 256, 0, stream>>>(Whh_w, Wt);
  gemm_bias_k<<<dim3(M / 128, H / 128), 256, 0, stream>>>(x, Whx_w, Whx_b, hid, M, H, DOBS);
  rnn_rec_k<<<BATCH * NSLICE, 256, 0, stream>>>(hid, y, Wt, Whh_b);
  gemm_bias_k<<<dim3(M / 128, H / 128), 256, 0, stream>>>(hid, Woh_w, Woh_b, y, M, H, H);
  softmax_k<<<2048, 256, 0, stream>>>(y, M);
}